// Round 5
// baseline (571.107 us; speedup 1.0000x reference)
//
#include <hip/hip_runtime.h>
#include <hip/hip_bf16.h>
#include <hip/hip_fp16.h>

#define N_NODES 50000
#define N_EDGES 500000
#define F_DIM   128
#define N_REL   8
#define N_LAYERS 2
#define NEG_SLOPE 0.2f

#define NBLK_N ((N_NODES + 255) / 256)   // 196 blocks over nodes

typedef _Float16 half8 __attribute__((ext_vector_type(8)));
typedef float f32x4  __attribute__((ext_vector_type(4)));

// ---------------- helpers ----------------

__device__ inline float lrelu(float l) { return (l > 0.f) ? l : NEG_SLOPE * l; }

__device__ inline void accum8h(float* a, uint4 v, float al) {
    const __half2* h2 = reinterpret_cast<const __half2*>(&v);
#pragma unroll
    for (int t = 0; t < 4; ++t) {
        float2 f = __half22float2(h2[t]);
        a[t * 2]     = fmaf(al, f.x, a[t * 2]);
        a[t * 2 + 1] = fmaf(al, f.y, a[t * 2 + 1]);
    }
}

// ---------------- H prep: fp32 [N,128] -> fp16 (row-major) ------------------
__global__ __launch_bounds__(256) void prep_h(const float* __restrict__ H,
                                              _Float16* __restrict__ Hf) {
    const size_t i8 = (size_t)blockIdx.x * 256 + threadIdx.x;   // 8-elem group
    if (i8 >= (size_t)N_NODES * F_DIM / 8) return;
    const float* src = H + i8 * 8;
    float av[8];
    *(float4*)(av)     = *(const float4*)(src);
    *(float4*)(av + 4) = *(const float4*)(src + 4);
    alignas(16) _Float16 hb[8];
#pragma unroll
    for (int j = 0; j < 8; ++j) hb[j] = (_Float16)av[j];
    *(uint4*)(Hf + i8 * 8) = *(const uint4*)hb;
}

// ---------------- W prep: W[l,r,f,g] fp32 -> Wf[l,r,g,f] fp16 ---------------
__global__ __launch_bounds__(256) void prep_w(const float* __restrict__ W,
                                              _Float16* __restrict__ Wf) {
    __shared__ float tile[64][F_DIM + 1];
    const int mat = blockIdx.x;                      // l*N_REL + r
    const float* src = W + (size_t)mat * F_DIM * F_DIM;
    const int t = threadIdx.x;
    for (int hf = 0; hf < 2; ++hf) {
#pragma unroll
        for (int i = 0; i < 8; ++i) {
            int idx = t + i * 256;
            int f = idx >> 5, c4 = idx & 31;
            float4 v = *(const float4*)(src + (size_t)(hf * 64 + f) * F_DIM + c4 * 4);
            *(float4*)&tile[f][c4 * 4] = v;
        }
        __syncthreads();
        int g = t >> 1, fs = (t & 1) * 32;
        for (int c = 0; c < 4; ++c) {
            alignas(16) _Float16 th[8];
#pragma unroll
            for (int j = 0; j < 8; ++j) th[j] = (_Float16)tile[fs + c * 8 + j][g];
            size_t o = ((size_t)mat * F_DIM + g) * F_DIM + hf * 64 + fs + c * 8;
            *(uint4*)(Wf + o) = *(const uint4*)th;
        }
        __syncthreads();
    }
}

// ---------------- attention vector prep: u_r = W_r q (and k) ----------------
// vb[l][c][f] fp16: c<8 -> q-vector of rel c; c>=8 -> k-vector of rel c-8.
// u_r[f] = sum_g W[l,r,f,g] * q[g]  (row-contiguous reads of W).
__global__ __launch_bounds__(256) void prep_vqk(const float* __restrict__ W,
                                                const float* __restrict__ att_q,
                                                const float* __restrict__ att_k,
                                                _Float16* __restrict__ vb) {
    const int l = blockIdx.x >> 3, r = blockIdx.x & 7;
    __shared__ float qk[2 * F_DIM];
    const int t = threadIdx.x;
    qk[t] = (t < F_DIM) ? att_q[l * F_DIM + t] : att_k[l * F_DIM + (t - F_DIM)];
    __syncthreads();
    const float* Wr = W + ((size_t)(l * N_REL + r)) * F_DIM * F_DIM;
    const int f = t & (F_DIM - 1);
    const float* qv = (t < F_DIM) ? qk : qk + F_DIM;
    float s = 0.f;
    for (int g = 0; g < F_DIM; g += 4) {
        float4 wv = *(const float4*)(Wr + (size_t)f * F_DIM + g);
        s += wv.x * qv[g] + wv.y * qv[g + 1] + wv.z * qv[g + 2] + wv.w * qv[g + 3];
    }
    const int c = (t < F_DIM) ? r : (N_REL + r);
    vb[((size_t)l * 16 + c) * F_DIM + f] = (_Float16)s;
}

// ---------------- a_q/a_k: [N,128] @ [128,16] MFMA --------------------------
// a_q[r][i] = h_i . u_r ; a_k[r][i] = h_i . v_r. One wave = 16 rows, 4 MFMAs.
__global__ __launch_bounds__(256) void aqk_kernel(const _Float16* __restrict__ Hf,
                                                  const _Float16* __restrict__ vbl,
                                                  float* __restrict__ a_q,
                                                  float* __restrict__ a_k) {
    const int w = threadIdx.x >> 6, lane = threadIdx.x & 63;
    const int q = lane >> 4, ln = lane & 15;
    const int row0 = blockIdx.x * 64 + w * 16;
    f32x4 acc = (f32x4)(0.f);
#pragma unroll
    for (int ks = 0; ks < 4; ++ks) {
        int rr = row0 + ln; if (rr >= N_NODES) rr = N_NODES - 1;
        half8 af = *(const half8*)(Hf + (size_t)rr * F_DIM + ks * 32 + q * 8);
        half8 bf = *(const half8*)(vbl + (size_t)ln * F_DIM + ks * 32 + q * 8);
        acc = __builtin_amdgcn_mfma_f32_16x16x32_f16(af, bf, acc, 0, 0, 0);
    }
#pragma unroll
    for (int reg = 0; reg < 4; ++reg) {
        const int row = row0 + q * 4 + reg;
        if (row < N_NODES) {
            if (ln < N_REL) a_q[ln * N_NODES + row] = acc[reg];
            else            a_k[(ln - N_REL) * N_NODES + row] = acc[reg];
        }
    }
}

// ---------------- CSR build (bucketed by (dst, rel)) ----------------

__global__ __launch_bounds__(256) void count2_kernel(const int* __restrict__ dstp,
                                                     const int* __restrict__ etp,
                                                     int* __restrict__ cnt2) {
    int e = blockIdx.x * 256 + threadIdx.x;
    if (e < N_EDGES) atomicAdd(cnt2 + dstp[e] * N_REL + etp[e], 1);
}

__global__ __launch_bounds__(256) void sum8_kernel(const int* __restrict__ cnt2,
                                                   int* __restrict__ cnt) {
    int d = blockIdx.x * 256 + threadIdx.x;
    if (d >= N_NODES) return;
    int4 a = *(const int4*)(cnt2 + d * 8);
    int4 b = *(const int4*)(cnt2 + d * 8 + 4);
    cnt[d] = a.x + a.y + a.z + a.w + b.x + b.y + b.z + b.w;
}

__global__ __launch_bounds__(256) void block_sum_kernel(const int* __restrict__ cnt,
                                                        int* __restrict__ partial) {
    __shared__ int s[256];
    int idx = blockIdx.x * 256 + threadIdx.x;
    int v = (idx < N_NODES) ? cnt[idx] : 0;
    s[threadIdx.x] = v;
    __syncthreads();
    for (int off = 128; off > 0; off >>= 1) {
        if (threadIdx.x < off) s[threadIdx.x] += s[threadIdx.x + off];
        __syncthreads();
    }
    if (threadIdx.x == 0) partial[blockIdx.x] = s[0];
}

__global__ __launch_bounds__(256) void scan_partials_kernel(int* __restrict__ partial,
                                                            int* __restrict__ row_ptr) {
    __shared__ int s[256];
    int t = threadIdx.x;
    int v = (t < NBLK_N) ? partial[t] : 0;
    s[t] = v;
    __syncthreads();
#pragma unroll
    for (int off = 1; off < 256; off <<= 1) {
        int x = (t >= off) ? s[t - off] : 0;
        __syncthreads();
        s[t] += x;
        __syncthreads();
    }
    if (t < NBLK_N) partial[t] = s[t] - v;
    if (t == 0) row_ptr[N_NODES] = N_EDGES;
}

__global__ __launch_bounds__(256) void scan_block_kernel(const int* __restrict__ cnt,
                                                         const int* __restrict__ partial,
                                                         int* __restrict__ row_ptr) {
    __shared__ int s[256];
    int t = threadIdx.x;
    int idx = blockIdx.x * 256 + t;
    int v = (idx < N_NODES) ? cnt[idx] : 0;
    s[t] = v;
    __syncthreads();
#pragma unroll
    for (int off = 1; off < 256; off <<= 1) {
        int x = (t >= off) ? s[t - off] : 0;
        __syncthreads();
        s[t] += x;
        __syncthreads();
    }
    if (idx < N_NODES) row_ptr[idx] = partial[blockIdx.x] + s[t] - v;
}

// per-node 8-way prefix: rp2[d*8+r] = row_ptr[d] + sum_{r'<r} cnt2[d*8+r']
__global__ __launch_bounds__(256) void rp2_kernel(const int* __restrict__ cnt2,
                                                  const int* __restrict__ row_ptr,
                                                  int* __restrict__ rp2) {
    int d = blockIdx.x * 256 + threadIdx.x;
    if (d == 0) rp2[(size_t)N_NODES * 8] = N_EDGES;
    if (d >= N_NODES) return;
    int4 a = *(const int4*)(cnt2 + d * 8);
    int4 b = *(const int4*)(cnt2 + d * 8 + 4);
    int rp = row_ptr[d];
    int o[8];
    o[0] = rp;          o[1] = o[0] + a.x;  o[2] = o[1] + a.y;  o[3] = o[2] + a.z;
    o[4] = o[3] + a.w;  o[5] = o[4] + b.x;  o[6] = o[5] + b.y;  o[7] = o[6] + b.z;
    *(int4*)(rp2 + d * 8)     = make_int4(o[0], o[1], o[2], o[3]);
    *(int4*)(rp2 + d * 8 + 4) = make_int4(o[4], o[5], o[6], o[7]);
}

__global__ __launch_bounds__(256) void scatter2_kernel(const int* __restrict__ srcp,
                                                       const int* __restrict__ dstp,
                                                       const int* __restrict__ etp,
                                                       const int* __restrict__ rp2,
                                                       int* __restrict__ cursor2,
                                                       unsigned* __restrict__ sorted,
                                                       unsigned short* __restrict__ dst16) {
    int e = blockIdx.x * 256 + threadIdx.x;
    if (e >= N_EDGES) return;
    int d = dstp[e], r = etp[e];
    int pos = atomicAdd(cursor2 + d * N_REL + r, 1);
    int j = rp2[d * N_REL + r] + pos;
    sorted[j] = (unsigned)srcp[e] | ((unsigned)r << 16);
    dst16[j] = (unsigned short)d;
}

// ---------------- edge-parallel logits --------------------------------------
__global__ __launch_bounds__(256) void logits_kernel(const float* __restrict__ a_q,
                                                     const float* __restrict__ a_k,
                                                     const unsigned* __restrict__ sorted,
                                                     const unsigned short* __restrict__ dst16,
                                                     float* __restrict__ lgt) {
    int j = blockIdx.x * 256 + threadIdx.x;
    if (j >= N_EDGES) return;
    unsigned p = sorted[j];
    int s = p & 0xffff, t = p >> 16;
    int d = dst16[j];
    lgt[j] = lrelu(a_q[t * N_NODES + d] + a_k[t * N_NODES + s]);
}

// ---------------- fused softmax + per-rel aggregate + MFMA W-apply ----------
// Block = 32 dst nodes (wave w owns nodes w*8..w*8+7 for softmax/gather).
// For each rel r: each wave builds LDS rows S[w*8+i] = sum_{e in (d,r)} ex_e *
// h_src (gather from L2/L3-resident Hf, NOT a 102MB xw buffer), absent rels
// write zero rows; then block MFMAs S[32x128] @ W_r[128x128] accumulating in
// registers (wave w owns cols w*32..w*32+31). Epilogue: /denom + bias + relu.
// S granules (8 floats) XOR-swizzled by row&15 for conflict-free MFMA A reads.
__global__ __launch_bounds__(256) void agg_mfma(const _Float16* __restrict__ Hf,
                                                const _Float16* __restrict__ Wf,
                                                const float* __restrict__ lgt,
                                                const unsigned* __restrict__ sorted,
                                                const int* __restrict__ rp2,
                                                const float* __restrict__ bias,
                                                float* __restrict__ outp,
                                                _Float16* __restrict__ hfp) {
    __shared__ float S[32][F_DIM];
    __shared__ float sm[32], sinv[32];
    const int tid = threadIdx.x, lane = tid & 63, w = tid >> 6;
    const int g = lane >> 4, ln = lane & 15;
    const int q = g;   // quad index alias (16-lane groups)
    const int base = blockIdx.x * 32;

    // ---- stage 0: bounds + edge cache + softmax for my 8 nodes ----
    int rpv[8];
    unsigned pc[8];
    float lc[8], ex[8];
    int beg_[8], deg_[8];
    const int lidx = (lane <= 8) ? lane : 8;
#pragma unroll
    for (int i = 0; i < 8; ++i) {
        int d = base + w * 8 + i;
        int dd = (d < N_NODES) ? d : (N_NODES - 1);
        rpv[i] = rp2[dd * 8 + lidx];
    }
#pragma unroll
    for (int i = 0; i < 8; ++i) {
        int b = __shfl(rpv[i], 0);
        int e = __shfl(rpv[i], 8);
        beg_[i] = b; deg_[i] = e - b;
        if (deg_[i] <= 64) {
            pc[i] = (lane < deg_[i]) ? sorted[b + lane] : 0u;
            lc[i] = (lane < deg_[i]) ? lgt[b + lane] : -3.4e38f;
        } else { pc[i] = 0u; lc[i] = -3.4e38f; }
    }
#pragma unroll
    for (int i = 0; i < 8; ++i) {
        if (deg_[i] <= 64) {
            float m = lc[i];
#pragma unroll
            for (int off = 32; off > 0; off >>= 1) m = fmaxf(m, __shfl_xor(m, off));
            float e0 = (lane < deg_[i]) ? __expf(lc[i] - m) : 0.f;
            ex[i] = e0;
            float ds = e0;
#pragma unroll
            for (int off = 32; off > 0; off >>= 1) ds += __shfl_xor(ds, off);
            if (lane == 0) { sm[w * 8 + i] = m; sinv[w * 8 + i] = 1.f / (ds + 1e-16f); }
        } else {
            ex[i] = 0.f;
            const int b = beg_[i], e = b + deg_[i];
            float m = -3.4e38f;
            for (int j = b + lane; j < e; j += 64) m = fmaxf(m, lgt[j]);
#pragma unroll
            for (int off = 32; off > 0; off >>= 1) m = fmaxf(m, __shfl_xor(m, off));
            float ds = 0.f;
            for (int j = b + lane; j < e; j += 64) ds += __expf(lgt[j] - m);
#pragma unroll
            for (int off = 32; off > 0; off >>= 1) ds += __shfl_xor(ds, off);
            if (lane == 0) { sm[w * 8 + i] = m; sinv[w * 8 + i] = 1.f / (ds + 1e-16f); }
        }
    }
    __syncthreads();

    f32x4 acc[2][2];
#pragma unroll
    for (int rt = 0; rt < 2; ++rt)
#pragma unroll
        for (int ct = 0; ct < 2; ++ct) acc[rt][ct] = (f32x4)(0.f);

#pragma unroll 1
    for (int r = 0; r < N_REL; ++r) {
        // ---- accumulate S rows for my 8 nodes, rel r ----
#pragma unroll
        for (int i = 0; i < 8; ++i) {
            const int sr = __shfl(rpv[i], r);
            const int er = __shfl(rpv[i], r + 1);
            const int cr = er - sr;
            const int row = w * 8 + i;
            if (cr == 0) {
                if (g == 0) {
                    float4* dp = (float4*)&S[row][(ln ^ (row & 15)) << 3];
                    dp[0] = make_float4(0.f, 0.f, 0.f, 0.f);
                    dp[1] = make_float4(0.f, 0.f, 0.f, 0.f);
                }
                continue;
            }
            float a8[8] = {0, 0, 0, 0, 0, 0, 0, 0};
            if (deg_[i] <= 64) {
                const int o = sr - beg_[i];
                for (int jj = 0; jj < cr; jj += 8) {
                    int j0 = (o + jj + g) & 63;
                    int j1 = (o + jj + 4 + g) & 63;
                    unsigned p0 = __shfl(pc[i], j0);
                    unsigned p1 = __shfl(pc[i], j1);
                    float a0 = __shfl(ex[i], j0);
                    float a1 = __shfl(ex[i], j1);
                    if (jj + g >= cr) a0 = 0.f;
                    if (jj + 4 + g >= cr) a1 = 0.f;
                    uint4 v0 = *(const uint4*)(Hf + (size_t)(p0 & 0xffff) * F_DIM + ln * 8);
                    uint4 v1 = *(const uint4*)(Hf + (size_t)(p1 & 0xffff) * F_DIM + ln * 8);
                    accum8h(a8, v0, a0);
                    accum8h(a8, v1, a1);
                }
            } else {  // rare high-degree path: edges straight from global
                const float mi = sm[row];
                for (int j = sr; j < er; j += 8) {
                    int i0 = j + g, i1 = j + 4 + g;
                    unsigned p0 = 0, p1 = 0;
                    float a0 = 0.f, a1 = 0.f;
                    if (i0 < er) { p0 = sorted[i0]; a0 = __expf(lgt[i0] - mi); }
                    if (i1 < er) { p1 = sorted[i1]; a1 = __expf(lgt[i1] - mi); }
                    uint4 v0 = *(const uint4*)(Hf + (size_t)(p0 & 0xffff) * F_DIM + ln * 8);
                    uint4 v1 = *(const uint4*)(Hf + (size_t)(p1 & 0xffff) * F_DIM + ln * 8);
                    accum8h(a8, v0, a0);
                    accum8h(a8, v1, a1);
                }
            }
#pragma unroll
            for (int t = 0; t < 8; ++t) {
                a8[t] += __shfl_xor(a8[t], 16);
                a8[t] += __shfl_xor(a8[t], 32);
            }
            if (g == 0) {
                float4* dp = (float4*)&S[row][(ln ^ (row & 15)) << 3];
                dp[0] = make_float4(a8[0], a8[1], a8[2], a8[3]);
                dp[1] = make_float4(a8[4], a8[5], a8[6], a8[7]);
            }
        }
        __syncthreads();

        // ---- MFMA: S[32x128] @ W_r -> acc (wave w: cols w*32..w*32+31) ----
        const _Float16* Wfr = Wf + (size_t)r * F_DIM * F_DIM;
#pragma unroll
        for (int ks = 0; ks < 4; ++ks) {
            half8 af[2];
#pragma unroll
            for (int rt = 0; rt < 2; ++rt) {
                const float* sp = &S[rt * 16 + ln][((ks * 4 + q) ^ ln) << 3];
                float4 f0 = *(const float4*)sp;
                float4 f1 = *((const float4*)sp + 1);
                af[rt][0] = (_Float16)f0.x; af[rt][1] = (_Float16)f0.y;
                af[rt][2] = (_Float16)f0.z; af[rt][3] = (_Float16)f0.w;
                af[rt][4] = (_Float16)f1.x; af[rt][5] = (_Float16)f1.y;
                af[rt][6] = (_Float16)f1.z; af[rt][7] = (_Float16)f1.w;
            }
            half8 bf[2];
#pragma unroll
            for (int ct = 0; ct < 2; ++ct)
                bf[ct] = *(const half8*)(Wfr + (size_t)((w * 2 + ct) * 16 + ln) * F_DIM + ks * 32 + q * 8);
#pragma unroll
            for (int rt = 0; rt < 2; ++rt)
#pragma unroll
                for (int ct = 0; ct < 2; ++ct)
                    acc[rt][ct] = __builtin_amdgcn_mfma_f32_16x16x32_f16(af[rt], bf[ct], acc[rt][ct], 0, 0, 0);
        }
        __syncthreads();
    }

    // ---- epilogue: /denom + bias + relu ----
#pragma unroll
    for (int rt = 0; rt < 2; ++rt)
#pragma unroll
        for (int ct = 0; ct < 2; ++ct) {
            const int col = (w * 2 + ct) * 16 + ln;
            const float bs = bias[col];
#pragma unroll
            for (int reg = 0; reg < 4; ++reg) {
                const int row = rt * 16 + q * 4 + reg;
                const int d = base + row;
                if (d < N_NODES) {
                    const float v = fmaxf(fmaf(acc[rt][ct][reg], sinv[row], bs), 0.f);
                    if (outp) outp[(size_t)d * F_DIM + col] = v;
                    if (hfp)  hfp[(size_t)d * F_DIM + col] = (_Float16)v;
                }
            }
        }
}

// ---------------- driver ----------------

extern "C" void kernel_launch(void* const* d_in, const int* in_sizes, int n_in,
                              void* d_out, int out_size, void* d_ws, size_t ws_size,
                              hipStream_t stream) {
    const float* x     = (const float*)d_in[0];
    const float* W     = (const float*)d_in[1];
    const float* att_q = (const float*)d_in[2];
    const float* att_k = (const float*)d_in[3];
    const float* bias  = (const float*)d_in[4];
    const int* ei      = (const int*)d_in[5];
    const int* etp     = (const int*)d_in[6];
    const int* srcp = ei;
    const int* dstp = ei + N_EDGES;
    float* out = (float*)d_out;
    char* ws   = (char*)d_ws;

    size_t off = 0;
    auto alloc = [&](size_t bytes) {
        void* p = ws + off;
        off = (off + bytes + 511) & ~(size_t)511;
        return p;
    };
    _Float16* Hf0    = (_Float16*)alloc((size_t)N_NODES * F_DIM * sizeof(_Float16));
    _Float16* Hf1    = (_Float16*)alloc((size_t)N_NODES * F_DIM * sizeof(_Float16));
    _Float16* Wf     = (_Float16*)alloc((size_t)N_LAYERS * N_REL * F_DIM * F_DIM * sizeof(_Float16));
    _Float16* vb     = (_Float16*)alloc((size_t)N_LAYERS * 16 * F_DIM * sizeof(_Float16));
    float* a_q       = (float*)alloc((size_t)N_REL * N_NODES * sizeof(float));
    float* a_k       = (float*)alloc((size_t)N_REL * N_NODES * sizeof(float));
    int* cnt2        = (int*)alloc((size_t)2 * N_NODES * N_REL * sizeof(int));  // cnt2 + cursor2
    int* cursor2     = cnt2 + (size_t)N_NODES * N_REL;
    int* cnt         = (int*)alloc((size_t)N_NODES * sizeof(int));
    int* row_ptr     = (int*)alloc(((size_t)N_NODES + 1) * sizeof(int));
    int* partial     = (int*)alloc(256 * sizeof(int));
    int* rp2         = (int*)alloc(((size_t)N_NODES * N_REL + 1) * sizeof(int));
    unsigned* sorted = (unsigned*)alloc((size_t)N_EDGES * sizeof(unsigned));
    unsigned short* dst16 = (unsigned short*)alloc((size_t)N_EDGES * sizeof(unsigned short));
    float* lgt       = (float*)alloc((size_t)N_EDGES * sizeof(float));

    prep_w<<<N_LAYERS * N_REL, 256, 0, stream>>>(W, Wf);
    prep_vqk<<<N_LAYERS * N_REL, 256, 0, stream>>>(W, att_q, att_k, vb);
    hipMemsetAsync(cnt2, 0, (size_t)2 * N_NODES * N_REL * sizeof(int), stream);
    count2_kernel<<<(N_EDGES + 255) / 256, 256, 0, stream>>>(dstp, etp, cnt2);
    sum8_kernel<<<NBLK_N, 256, 0, stream>>>(cnt2, cnt);
    block_sum_kernel<<<NBLK_N, 256, 0, stream>>>(cnt, partial);
    scan_partials_kernel<<<1, 256, 0, stream>>>(partial, row_ptr);
    scan_block_kernel<<<NBLK_N, 256, 0, stream>>>(cnt, partial, row_ptr);
    rp2_kernel<<<NBLK_N, 256, 0, stream>>>(cnt2, row_ptr, rp2);
    scatter2_kernel<<<(N_EDGES + 255) / 256, 256, 0, stream>>>(
        srcp, dstp, etp, rp2, cursor2, sorted, dst16);

    const int grid_h = (N_NODES * F_DIM / 8 + 255) / 256;   // 3125
    const int grid_e = (N_EDGES + 255) / 256;               // 1954
    const int grid_a = (N_NODES + 63) / 64;                 // 782
    const int grid_f = (N_NODES + 31) / 32;                 // 1563
    prep_h<<<grid_h, 256, 0, stream>>>(x, Hf0);
    for (int l = 0; l < N_LAYERS; ++l) {
        const _Float16* Hin = (l == 0) ? Hf0 : Hf1;
        const bool last = (l == N_LAYERS - 1);
        aqk_kernel<<<grid_a, 256, 0, stream>>>(Hin, vb + (size_t)l * 16 * F_DIM, a_q, a_k);
        logits_kernel<<<grid_e, 256, 0, stream>>>(a_q, a_k, sorted, dst16, lgt);
        agg_mfma<<<grid_f, 256, 0, stream>>>(
            Hin, Wf + (size_t)l * N_REL * F_DIM * F_DIM, lgt, sorted, rp2,
            bias + l * F_DIM,
            last ? out : nullptr,
            last ? nullptr : Hf1);
    }
}

// Round 6
// 365.198 us; speedup vs baseline: 1.5638x; 1.5638x over previous
//
#include <hip/hip_runtime.h>
#include <hip/hip_bf16.h>
#include <hip/hip_fp16.h>

#define N_NODES 50000
#define N_EDGES 500000
#define F_DIM   128
#define N_REL   8
#define N_LAYERS 2
#define NEG_SLOPE 0.2f

#define NBLK_N ((N_NODES + 255) / 256)   // 196 blocks over nodes

typedef _Float16 half8 __attribute__((ext_vector_type(8)));
typedef float f32x4  __attribute__((ext_vector_type(4)));

// ---------------- helpers ----------------

__device__ inline float lrelu(float l) { return (l > 0.f) ? l : NEG_SLOPE * l; }

// ---------------- H prep: fp32 [N,128] -> fp16 (row-major) ------------------
__global__ __launch_bounds__(256) void prep_h(const float* __restrict__ H,
                                              _Float16* __restrict__ Hf) {
    const size_t i8 = (size_t)blockIdx.x * 256 + threadIdx.x;   // 8-elem group
    if (i8 >= (size_t)N_NODES * F_DIM / 8) return;
    const float* src = H + i8 * 8;
    float av[8];
    *(float4*)(av)     = *(const float4*)(src);
    *(float4*)(av + 4) = *(const float4*)(src + 4);
    alignas(16) _Float16 hb[8];
#pragma unroll
    for (int j = 0; j < 8; ++j) hb[j] = (_Float16)av[j];
    *(uint4*)(Hf + i8 * 8) = *(const uint4*)hb;
}

// ---------------- W prep: W[l,r,f,g] fp32 -> Wf[l,r,g,f] fp16 ---------------
__global__ __launch_bounds__(256) void prep_w(const float* __restrict__ W,
                                              _Float16* __restrict__ Wf) {
    __shared__ float tile[64][F_DIM + 1];
    const int mat = blockIdx.x;                      // l*N_REL + r
    const float* src = W + (size_t)mat * F_DIM * F_DIM;
    const int t = threadIdx.x;
    for (int hf = 0; hf < 2; ++hf) {
#pragma unroll
        for (int i = 0; i < 8; ++i) {
            int idx = t + i * 256;
            int f = idx >> 5, c4 = idx & 31;
            float4 v = *(const float4*)(src + (size_t)(hf * 64 + f) * F_DIM + c4 * 4);
            *(float4*)&tile[f][c4 * 4] = v;
        }
        __syncthreads();
        int g = t >> 1, fs = (t & 1) * 32;
        for (int c = 0; c < 4; ++c) {
            alignas(16) _Float16 th[8];
#pragma unroll
            for (int j = 0; j < 8; ++j) th[j] = (_Float16)tile[fs + c * 8 + j][g];
            size_t o = ((size_t)mat * F_DIM + g) * F_DIM + hf * 64 + fs + c * 8;
            *(uint4*)(Wf + o) = *(const uint4*)th;
        }
        __syncthreads();
    }
}

// ---------------- A-stationary fp16 MFMA GEMM, 32 rows/wave -----------------
// grid (391, 8), 256 threads (4 waves), ONE relation per block. NO LDS, NO
// barriers: all 4 waves read the same L1/L2-resident W[r] (32 KB, shared by
// 391 blocks of this relation), so B-fragments load straight from global and
// pipeline against the MFMAs. Block: load A regs -> 4x{8 B-frag loads + 16
// MFMA} -> epilogue stores. LDS_Block_Size=0 lifts the LDS occupancy cap.
// xw stored COLUMN-PERMUTED: xw'[row][ln*8+t] = C[row][t*16+ln].
// a_q/a_k stored [rel][node] (coalesced epilogue writes).
#define GBM 128
__global__ __launch_bounds__(256, 2) void gemm_xw(const _Float16* __restrict__ Hf,
                                                  const _Float16* __restrict__ Wf,
                                                  const float* __restrict__ qv_g,
                                                  const float* __restrict__ kv_g,
                                                  __half* __restrict__ xw,
                                                  float* __restrict__ a_q,
                                                  float* __restrict__ a_k) {
    const int rb0 = blockIdx.x * GBM;
    const int r   = blockIdx.y;
    const int tid = threadIdx.x;
    const int lane = tid & 63, w = tid >> 6;
    const int q = lane >> 4, ln = lane & 15;
    const _Float16* __restrict__ Wfr = Wf + (size_t)r * F_DIM * F_DIM;

    // pinned fp16 A for this lane's two row-tiles
    half8 Af[2][4];
#pragma unroll
    for (int rt = 0; rt < 2; ++rt) {
        int row = rb0 + w * 32 + rt * 16 + ln;
        int ar = (row < N_NODES) ? row : (N_NODES - 1);
        const _Float16* hp = Hf + (size_t)ar * F_DIM;
#pragma unroll
        for (int ks = 0; ks < 4; ++ks)
            Af[rt][ks] = *(const half8*)(hp + ks * 32 + q * 8);
    }

    float qvl[8], kvl[8];
#pragma unroll
    for (int t = 0; t < 8; ++t) {
        qvl[t] = qv_g[t * 16 + ln];
        kvl[t] = kv_g[t * 16 + ln];
    }

    f32x4 acc[2][8];
#pragma unroll
    for (int rt = 0; rt < 2; ++rt)
#pragma unroll
        for (int t = 0; t < 8; ++t) acc[rt][t] = (f32x4)(0.f);

#pragma unroll
    for (int ks = 0; ks < 4; ++ks) {
        half8 Bf[8];
#pragma unroll
        for (int c = 0; c < 8; ++c)
            Bf[c] = *(const half8*)(Wfr + (size_t)(c * 16 + ln) * F_DIM + ks * 32 + q * 8);
        // 16 independent accumulator chains; each B feeds 2 MFMAs
#pragma unroll
        for (int c = 0; c < 8; ++c)
#pragma unroll
            for (int rt = 0; rt < 2; ++rt)
                acc[rt][c] = __builtin_amdgcn_mfma_f32_16x16x32_f16(Af[rt][ks], Bf[c], acc[rt][c], 0, 0, 0);
    }

    // epilogue: permuted 16B stores + in-wave q/k dots (no atomics)
#pragma unroll
    for (int rt = 0; rt < 2; ++rt) {
        float pq[4], pk[4];
#pragma unroll
        for (int reg = 0; reg < 4; ++reg) {
            const int row = rb0 + w * 32 + rt * 16 + q * 4 + reg;
            alignas(16) unsigned short hs[8];
            float sq = 0.f, sk = 0.f;
#pragma unroll
            for (int t = 0; t < 8; ++t) {
                float v = acc[rt][t][reg];
                __half hv = __float2half(v);
                hs[t] = *reinterpret_cast<unsigned short*>(&hv);
                sq = fmaf(v, qvl[t], sq);
                sk = fmaf(v, kvl[t], sk);
            }
            if (row < N_NODES)
                *(uint4*)(xw + ((size_t)r * N_NODES + row) * F_DIM + ln * 8) = *(const uint4*)hs;
            pq[reg] = sq; pk[reg] = sk;
        }
#pragma unroll
        for (int reg = 0; reg < 4; ++reg) {
#pragma unroll
            for (int m = 1; m <= 8; m <<= 1) {
                pq[reg] += __shfl_xor(pq[reg], m);
                pk[reg] += __shfl_xor(pk[reg], m);
            }
        }
        if (ln == 0) {
#pragma unroll
            for (int reg = 0; reg < 4; ++reg) {
                const int row = rb0 + w * 32 + rt * 16 + q * 4 + reg;
                if (row < N_NODES) {
                    a_q[r * N_NODES + row] = pq[reg];
                    a_k[r * N_NODES + row] = pk[reg];
                }
            }
        }
    }
}

// ---------------- CSR build ----------------

__global__ __launch_bounds__(256) void count_kernel(const int* __restrict__ dstp,
                                                    int* __restrict__ cnt) {
    int e = blockIdx.x * 256 + threadIdx.x;
    if (e < N_EDGES) atomicAdd(cnt + dstp[e], 1);
}

__global__ __launch_bounds__(256) void block_sum_kernel(const int* __restrict__ cnt,
                                                        int* __restrict__ partial) {
    __shared__ int s[256];
    int idx = blockIdx.x * 256 + threadIdx.x;
    int v = (idx < N_NODES) ? cnt[idx] : 0;
    s[threadIdx.x] = v;
    __syncthreads();
    for (int off = 128; off > 0; off >>= 1) {
        if (threadIdx.x < off) s[threadIdx.x] += s[threadIdx.x + off];
        __syncthreads();
    }
    if (threadIdx.x == 0) partial[blockIdx.x] = s[0];
}

__global__ __launch_bounds__(256) void scan_partials_kernel(int* __restrict__ partial,
                                                            int* __restrict__ row_ptr) {
    __shared__ int s[256];
    int t = threadIdx.x;
    int v = (t < NBLK_N) ? partial[t] : 0;
    s[t] = v;
    __syncthreads();
#pragma unroll
    for (int off = 1; off < 256; off <<= 1) {
        int x = (t >= off) ? s[t - off] : 0;
        __syncthreads();
        s[t] += x;
        __syncthreads();
    }
    if (t < NBLK_N) partial[t] = s[t] - v;
    if (t == 0) row_ptr[N_NODES] = N_EDGES;
}

__global__ __launch_bounds__(256) void scan_block_kernel(const int* __restrict__ cnt,
                                                         const int* __restrict__ partial,
                                                         int* __restrict__ row_ptr) {
    __shared__ int s[256];
    int t = threadIdx.x;
    int idx = blockIdx.x * 256 + t;
    int v = (idx < N_NODES) ? cnt[idx] : 0;
    s[t] = v;
    __syncthreads();
#pragma unroll
    for (int off = 1; off < 256; off <<= 1) {
        int x = (t >= off) ? s[t - off] : 0;
        __syncthreads();
        s[t] += x;
        __syncthreads();
    }
    if (idx < N_NODES) row_ptr[idx] = partial[blockIdx.x] + s[t] - v;
}

__global__ __launch_bounds__(256) void scatter_kernel(const int* __restrict__ srcp,
                                                      const int* __restrict__ dstp,
                                                      const int* __restrict__ etp,
                                                      const int* __restrict__ row_ptr,
                                                      int* __restrict__ cursor,
                                                      unsigned* __restrict__ sorted,
                                                      unsigned short* __restrict__ dst16) {
    int e = blockIdx.x * 256 + threadIdx.x;
    if (e >= N_EDGES) return;
    int d = dstp[e];
    int pos = atomicAdd(cursor + d, 1);
    int j = row_ptr[d] + pos;
    sorted[j] = (unsigned)srcp[e] | ((unsigned)etp[e] << 16);
    dst16[j] = (unsigned short)d;
}

// ---------------- edge-parallel logits --------------------------------------
// Hoists the scattered a_q/a_k gathers out of agg_fused's serial chain into a
// kernel with massive TLP. a_q reads are near-uniform per wave (edges are
// dst-sorted); a_k scattered reads stay L2-resident (1.6 MB).
__global__ __launch_bounds__(256) void logits_kernel(const float* __restrict__ a_q,
                                                     const float* __restrict__ a_k,
                                                     const unsigned* __restrict__ sorted,
                                                     const unsigned short* __restrict__ dst16,
                                                     float* __restrict__ lgt) {
    int j = blockIdx.x * 256 + threadIdx.x;
    if (j >= N_EDGES) return;
    unsigned p = sorted[j];
    int s = p & 0xffff, t = p >> 16;
    int d = dst16[j];
    lgt[j] = lrelu(a_q[t * N_NODES + d] + a_k[t * N_NODES + s]);
}

// ---------------- fused softmax + aggregate + bias + relu ----------------
// xw is column-permuted: position p holds col (p&7)*16 + (p>>3).
// outp (fp32) and/or hfp (fp16, next layer's A operand) may be null.
// Logits precomputed (lgt, coalesced load); gather runs on ex weights,
// denominator reduce + single divide deferred past the gather loop.
__device__ inline void accum8(float* acc, uint4 v, float a) {
    const __half2* h2 = reinterpret_cast<const __half2*>(&v);
#pragma unroll
    for (int t = 0; t < 4; ++t) {
        float2 f = __half22float2(h2[t]);
        acc[t * 2]     = fmaf(a, f.x, acc[t * 2]);
        acc[t * 2 + 1] = fmaf(a, f.y, acc[t * 2 + 1]);
    }
}
__device__ inline const uint4* xwrow(const __half* xw, unsigned p, int ln) {
    return (const uint4*)(xw + (((size_t)(p >> 16)) * N_NODES + (p & 0xffff)) * F_DIM + ln * 8);
}

__global__ __launch_bounds__(256) void agg_fused(const __half* __restrict__ xw,
                                                 const float* __restrict__ lgt,
                                                 const int* __restrict__ row_ptr,
                                                 const unsigned* __restrict__ sorted,
                                                 const float* __restrict__ bias,
                                                 float* __restrict__ outp,
                                                 _Float16* __restrict__ hfp) {
    const int lane = threadIdx.x & 63;
    const int wave = threadIdx.x >> 6;
    const int d = blockIdx.x * 4 + wave;
    if (d >= N_NODES) return;
    const int beg = row_ptr[d], end = row_ptr[d + 1];
    const int cnt = end - beg;
    const int g = lane >> 4, ln = lane & 15;   // 4 edge-groups x 16 col-lanes

    if (cnt <= 64) {
        // one edge per lane; lanes >= cnt carry p=0 (valid dummy row) ex=0,
        // so the gather loop needs no masking.
        unsigned p = 0;
        float l = -3.4e38f;
        if (lane < cnt) {
            p = sorted[beg + lane];
            l = lgt[beg + lane];
        }
        float m = l;
#pragma unroll
        for (int off = 32; off > 0; off >>= 1) m = fmaxf(m, __shfl_xor(m, off));
        const float ex = (lane < cnt) ? __expf(l - m) : 0.f;

        float acc[8] = {0, 0, 0, 0, 0, 0, 0, 0};
        for (int i = 0; i < cnt; i += 8) {
            unsigned p0 = __shfl(p, i + g);
            unsigned p1 = __shfl(p, i + 4 + g);
            float a0 = __shfl(ex, i + g);
            float a1 = __shfl(ex, i + 4 + g);
            uint4 v0 = *xwrow(xw, p0, ln);
            uint4 v1 = *xwrow(xw, p1, ln);
            accum8(acc, v0, a0);
            accum8(acc, v1, a1);
        }
        // denom + accumulator reduction off the gather critical path
        float dsum = ex;
#pragma unroll
        for (int off = 32; off > 0; off >>= 1) dsum += __shfl_xor(dsum, off);
#pragma unroll
        for (int t = 0; t < 8; ++t) {
            acc[t] += __shfl_xor(acc[t], 16);
            acc[t] += __shfl_xor(acc[t], 32);
        }
        if (g == 0) {
            const float inv = 1.f / (dsum + 1e-16f);
#pragma unroll
            for (int t = 0; t < 8; ++t) {
                const int col = t * 16 + ln;
                const float v = fmaxf(fmaf(acc[t], inv, bias[col]), 0.f);
                if (outp) outp[(size_t)d * F_DIM + col] = v;
                if (hfp)  hfp[(size_t)d * F_DIM + col] = (_Float16)v;
            }
        }
    } else {
        // rare high-degree fallback: per-lane 2-col scalar path
        const int p0 = lane * 2;
        const int c0 = (p0 & 7) * 16 + (p0 >> 3);
        const int c1 = c0 + 16;
        float2 acc = make_float2(bias[c0], bias[c1]);
        float m = -3.4e38f;
        for (int i = beg + lane; i < end; i += 64) m = fmaxf(m, lgt[i]);
#pragma unroll
        for (int off = 32; off > 0; off >>= 1) m = fmaxf(m, __shfl_xor(m, off));
        float dsum = 0.f;
        for (int i = beg + lane; i < end; i += 64) dsum += __expf(lgt[i] - m);
#pragma unroll
        for (int off = 32; off > 0; off >>= 1) dsum += __shfl_xor(dsum, off);
        const float inv = 1.f / (dsum + 1e-16f);
        for (int i = beg; i < end; ++i) {
            unsigned p = sorted[i];
            float alpha = __expf(lgt[i] - m) * inv;
            const __half2 h2 = *((const __half2*)xw + (((size_t)(p >> 16)) * N_NODES + (p & 0xffff)) * (F_DIM / 2) + lane);
            float2 v = make_float2(__half2float(h2.x), __half2float(h2.y));
            acc.x = fmaf(alpha, v.x, acc.x);
            acc.y = fmaf(alpha, v.y, acc.y);
        }
        const float v0 = fmaxf(acc.x, 0.f), v1 = fmaxf(acc.y, 0.f);
        if (outp) { outp[(size_t)d * F_DIM + c0] = v0; outp[(size_t)d * F_DIM + c1] = v1; }
        if (hfp)  { hfp[(size_t)d * F_DIM + c0] = (_Float16)v0; hfp[(size_t)d * F_DIM + c1] = (_Float16)v1; }
    }
}

// ---------------- driver ----------------

extern "C" void kernel_launch(void* const* d_in, const int* in_sizes, int n_in,
                              void* d_out, int out_size, void* d_ws, size_t ws_size,
                              hipStream_t stream) {
    const float* x     = (const float*)d_in[0];
    const float* W     = (const float*)d_in[1];
    const float* att_q = (const float*)d_in[2];
    const float* att_k = (const float*)d_in[3];
    const float* bias  = (const float*)d_in[4];
    const int* ei      = (const int*)d_in[5];
    const int* etp     = (const int*)d_in[6];
    const int* srcp = ei;
    const int* dstp = ei + N_EDGES;
    float* out = (float*)d_out;
    char* ws   = (char*)d_ws;

    size_t off = 0;
    auto alloc = [&](size_t bytes) {
        void* p = ws + off;
        off = (off + bytes + 511) & ~(size_t)511;
        return p;
    };
    __half* xw       = (__half*)alloc((size_t)N_REL * N_NODES * F_DIM * sizeof(__half));
    float* a_q       = (float*)alloc((size_t)N_REL * N_NODES * sizeof(float));
    float* a_k       = (float*)alloc((size_t)N_REL * N_NODES * sizeof(float));
    int* cnt         = (int*)alloc((size_t)2 * N_NODES * sizeof(int));  // cnt + cursor, one memset
    int* cursor      = cnt + N_NODES;
    int* row_ptr     = (int*)alloc(((size_t)N_NODES + 1) * sizeof(int));
    int* partial     = (int*)alloc(256 * sizeof(int));
    unsigned* sorted = (unsigned*)alloc((size_t)N_EDGES * sizeof(unsigned));
    unsigned short* dst16 = (unsigned short*)alloc((size_t)N_EDGES * sizeof(unsigned short));
    float* lgt       = (float*)alloc((size_t)N_EDGES * sizeof(float));
    _Float16* Wf     = (_Float16*)alloc((size_t)N_LAYERS * N_REL * F_DIM * F_DIM * sizeof(_Float16));
    _Float16* Hf     = (_Float16*)alloc((size_t)N_NODES * F_DIM * sizeof(_Float16));

    prep_w<<<N_LAYERS * N_REL, 256, 0, stream>>>(W, Wf);
    hipMemsetAsync(cnt, 0, (size_t)2 * N_NODES * 4, stream);
    count_kernel<<<(N_EDGES + 255) / 256, 256, 0, stream>>>(dstp, cnt);
    block_sum_kernel<<<NBLK_N, 256, 0, stream>>>(cnt, partial);
    scan_partials_kernel<<<1, 256, 0, stream>>>(partial, row_ptr);
    scan_block_kernel<<<NBLK_N, 256, 0, stream>>>(cnt, partial, row_ptr);
    scatter_kernel<<<(N_EDGES + 255) / 256, 256, 0, stream>>>(
        srcp, dstp, etp, row_ptr, cursor, sorted, dst16);

    const int grid_h = (N_NODES * F_DIM / 8 + 255) / 256;   // 3125
    const int grid_m = (N_NODES + GBM - 1) / GBM;           // 391
    const int grid_e = (N_EDGES + 255) / 256;               // 1954
    prep_h<<<grid_h, 256, 0, stream>>>(x, Hf);              // layer-0 input only
    for (int l = 0; l < N_LAYERS; ++l) {
        gemm_xw<<<dim3(grid_m, N_REL), 256, 0, stream>>>(
            Hf, Wf + (size_t)l * N_REL * F_DIM * F_DIM,
            att_q + l * F_DIM, att_k + l * F_DIM,
            xw, a_q, a_k);
        logits_kernel<<<grid_e, 256, 0, stream>>>(a_q, a_k, sorted, dst16, lgt);
        const bool last = (l == N_LAYERS - 1);
        agg_fused<<<(N_NODES + 3) / 4, 256, 0, stream>>>(
            xw, lgt, row_ptr, sorted, bias + l * F_DIM,
            last ? out : nullptr,
            last ? nullptr : Hf);
    }
}

// Round 7
// 291.581 us; speedup vs baseline: 1.9587x; 1.2525x over previous
//
#include <hip/hip_runtime.h>
#include <hip/hip_bf16.h>
#include <hip/hip_fp16.h>

#define N_NODES 50000
#define N_EDGES 500000
#define F_DIM   128
#define N_REL   8
#define N_LAYERS 2
#define NEG_SLOPE 0.2f

#define NBLK_N ((N_NODES + 255) / 256)   // 196 blocks over nodes

typedef _Float16 half8 __attribute__((ext_vector_type(8)));
typedef float f32x4  __attribute__((ext_vector_type(4)));

// ---------------- helpers ----------------

__device__ inline float lrelu(float l) { return (l > 0.f) ? l : NEG_SLOPE * l; }

// ---------------- H prep: fp32 [N,128] -> fp16 (row-major) ------------------
__global__ __launch_bounds__(256) void prep_h(const float* __restrict__ H,
                                              _Float16* __restrict__ Hf) {
    const size_t i8 = (size_t)blockIdx.x * 256 + threadIdx.x;   // 8-elem group
    if (i8 >= (size_t)N_NODES * F_DIM / 8) return;
    const float* src = H + i8 * 8;
    float av[8];
    *(float4*)(av)     = *(const float4*)(src);
    *(float4*)(av + 4) = *(const float4*)(src + 4);
    alignas(16) _Float16 hb[8];
#pragma unroll
    for (int j = 0; j < 8; ++j) hb[j] = (_Float16)av[j];
    *(uint4*)(Hf + i8 * 8) = *(const uint4*)hb;
}

// ---------------- W prep: W[l,r,f,g] fp32 -> Wf[l,r,g,f] fp16 ---------------
__global__ __launch_bounds__(256) void prep_w(const float* __restrict__ W,
                                              _Float16* __restrict__ Wf) {
    __shared__ float tile[64][F_DIM + 1];
    const int mat = blockIdx.x;                      // l*N_REL + r
    const float* src = W + (size_t)mat * F_DIM * F_DIM;
    const int t = threadIdx.x;
    for (int hf = 0; hf < 2; ++hf) {
#pragma unroll
        for (int i = 0; i < 8; ++i) {
            int idx = t + i * 256;
            int f = idx >> 5, c4 = idx & 31;
            float4 v = *(const float4*)(src + (size_t)(hf * 64 + f) * F_DIM + c4 * 4);
            *(float4*)&tile[f][c4 * 4] = v;
        }
        __syncthreads();
        int g = t >> 1, fs = (t & 1) * 32;
        for (int c = 0; c < 4; ++c) {
            alignas(16) _Float16 th[8];
#pragma unroll
            for (int j = 0; j < 8; ++j) th[j] = (_Float16)tile[fs + c * 8 + j][g];
            size_t o = ((size_t)mat * F_DIM + g) * F_DIM + hf * 64 + fs + c * 8;
            *(uint4*)(Wf + o) = *(const uint4*)th;
        }
        __syncthreads();
    }
}

// ---------------- A-stationary fp16 MFMA GEMM, staged W, 4 tiles/block ------
// grid (98, 8), 256 threads (4 waves), ONE relation per block. Stage 32KB W[r]
// into XOR-swizzled LDS ONCE, single barrier, then 4 sequential 128-row tiles:
// {load A regs, 64 MFMA/wave, epilogue stores}. No barrier between tiles (LDS
// is read-only after stage), so tile-t stores drain under tile-t+1 compute;
// staging traffic and barriers amortized 4x vs the 1-tile version.
// xw stored COLUMN-PERMUTED: xw'[row][ln*8+t] = C[row][t*16+ln].
// a_q/a_k stored [rel][node] (coalesced epilogue writes).
#define GBM 512
__global__ __launch_bounds__(256, 2) void gemm_xw(const _Float16* __restrict__ Hf,
                                                  const _Float16* __restrict__ Wf,
                                                  const float* __restrict__ qv_g,
                                                  const float* __restrict__ kv_g,
                                                  __half* __restrict__ xw,
                                                  float* __restrict__ a_q,
                                                  float* __restrict__ a_k) {
    __shared__ _Float16 lds[F_DIM * F_DIM];    // 32 KB, [col][f] XOR-swizzled
    const int r   = blockIdx.y;
    const int tid = threadIdx.x;
    const int lane = tid & 63, w = tid >> 6;
    const int q = lane >> 4, ln = lane & 15;

    // stage W[r] fp16: 2048 16B chunks, 8 per thread, XOR-swizzled
    {
        const _Float16* src = Wf + (size_t)r * F_DIM * F_DIM;
#pragma unroll
        for (int i = 0; i < 8; ++i) {
            int chunk = tid + i * 256;               // [0, 2048)
            int gg = chunk >> 4, c8 = chunk & 15;
            uint4 v = *(const uint4*)(src + gg * F_DIM + c8 * 8);
            *(uint4*)(lds + gg * F_DIM + ((c8 ^ (gg & 15)) * 8)) = v;
        }
    }

    float qvl[8], kvl[8];
#pragma unroll
    for (int t = 0; t < 8; ++t) {
        qvl[t] = qv_g[t * 16 + ln];
        kvl[t] = kv_g[t * 16 + ln];
    }

    __syncthreads();   // W staged; only barrier in the kernel

    for (int t4 = 0; t4 < 4; ++t4) {
        const int rb0 = blockIdx.x * GBM + t4 * 128;
        if (rb0 >= N_NODES) break;

        // pinned fp16 A for this lane's two row-tiles
        half8 Af[2][4];
#pragma unroll
        for (int rt = 0; rt < 2; ++rt) {
            int row = rb0 + w * 32 + rt * 16 + ln;
            int ar = (row < N_NODES) ? row : (N_NODES - 1);
            const _Float16* hp = Hf + (size_t)ar * F_DIM;
#pragma unroll
            for (int ks = 0; ks < 4; ++ks)
                Af[rt][ks] = *(const half8*)(hp + ks * 32 + q * 8);
        }

        f32x4 acc[2][8];
#pragma unroll
        for (int rt = 0; rt < 2; ++rt)
#pragma unroll
            for (int t = 0; t < 8; ++t) acc[rt][t] = (f32x4)(0.f);

#pragma unroll
        for (int ks = 0; ks < 4; ++ks) {
            const int jx = (((ks * 4 + q) ^ ln)) << 3;   // swizzled 16B chunk
            half8 Bf[8];
#pragma unroll
            for (int c = 0; c < 8; ++c)
                Bf[c] = *(const half8*)(lds + (c * 16 + ln) * F_DIM + jx);
            // 16 independent accumulator chains; each B feeds 2 MFMAs
#pragma unroll
            for (int c = 0; c < 8; ++c)
#pragma unroll
                for (int rt = 0; rt < 2; ++rt)
                    acc[rt][c] = __builtin_amdgcn_mfma_f32_16x16x32_f16(Af[rt][ks], Bf[c], acc[rt][c], 0, 0, 0);
        }

        // epilogue: permuted 16B stores + in-wave q/k dots (no atomics)
#pragma unroll
        for (int rt = 0; rt < 2; ++rt) {
            float pq[4], pk[4];
#pragma unroll
            for (int reg = 0; reg < 4; ++reg) {
                const int row = rb0 + w * 32 + rt * 16 + q * 4 + reg;
                alignas(16) unsigned short hs[8];
                float sq = 0.f, sk = 0.f;
#pragma unroll
                for (int t = 0; t < 8; ++t) {
                    float v = acc[rt][t][reg];
                    __half hv = __float2half(v);
                    hs[t] = *reinterpret_cast<unsigned short*>(&hv);
                    sq = fmaf(v, qvl[t], sq);
                    sk = fmaf(v, kvl[t], sk);
                }
                if (row < N_NODES)
                    *(uint4*)(xw + ((size_t)r * N_NODES + row) * F_DIM + ln * 8) = *(const uint4*)hs;
                pq[reg] = sq; pk[reg] = sk;
            }
#pragma unroll
            for (int reg = 0; reg < 4; ++reg) {
#pragma unroll
                for (int m = 1; m <= 8; m <<= 1) {
                    pq[reg] += __shfl_xor(pq[reg], m);
                    pk[reg] += __shfl_xor(pk[reg], m);
                }
            }
            if (ln == 0) {
#pragma unroll
                for (int reg = 0; reg < 4; ++reg) {
                    const int row = rb0 + w * 32 + rt * 16 + q * 4 + reg;
                    if (row < N_NODES) {
                        a_q[r * N_NODES + row] = pq[reg];
                        a_k[r * N_NODES + row] = pk[reg];
                    }
                }
            }
        }
    }
}

// ---------------- CSR build ----------------

__global__ __launch_bounds__(256) void count_kernel(const int* __restrict__ dstp,
                                                    int* __restrict__ cnt) {
    int e = blockIdx.x * 256 + threadIdx.x;
    if (e < N_EDGES) atomicAdd(cnt + dstp[e], 1);
}

__global__ __launch_bounds__(256) void block_sum_kernel(const int* __restrict__ cnt,
                                                        int* __restrict__ partial) {
    __shared__ int s[256];
    int idx = blockIdx.x * 256 + threadIdx.x;
    int v = (idx < N_NODES) ? cnt[idx] : 0;
    s[threadIdx.x] = v;
    __syncthreads();
    for (int off = 128; off > 0; off >>= 1) {
        if (threadIdx.x < off) s[threadIdx.x] += s[threadIdx.x + off];
        __syncthreads();
    }
    if (threadIdx.x == 0) partial[blockIdx.x] = s[0];
}

__global__ __launch_bounds__(256) void scan_partials_kernel(int* __restrict__ partial,
                                                            int* __restrict__ row_ptr) {
    __shared__ int s[256];
    int t = threadIdx.x;
    int v = (t < NBLK_N) ? partial[t] : 0;
    s[t] = v;
    __syncthreads();
#pragma unroll
    for (int off = 1; off < 256; off <<= 1) {
        int x = (t >= off) ? s[t - off] : 0;
        __syncthreads();
        s[t] += x;
        __syncthreads();
    }
    if (t < NBLK_N) partial[t] = s[t] - v;
    if (t == 0) row_ptr[N_NODES] = N_EDGES;
}

__global__ __launch_bounds__(256) void scan_block_kernel(const int* __restrict__ cnt,
                                                         const int* __restrict__ partial,
                                                         int* __restrict__ row_ptr) {
    __shared__ int s[256];
    int t = threadIdx.x;
    int idx = blockIdx.x * 256 + t;
    int v = (idx < N_NODES) ? cnt[idx] : 0;
    s[t] = v;
    __syncthreads();
#pragma unroll
    for (int off = 1; off < 256; off <<= 1) {
        int x = (t >= off) ? s[t - off] : 0;
        __syncthreads();
        s[t] += x;
        __syncthreads();
    }
    if (idx < N_NODES) row_ptr[idx] = partial[blockIdx.x] + s[t] - v;
}

__global__ __launch_bounds__(256) void scatter_kernel(const int* __restrict__ srcp,
                                                      const int* __restrict__ dstp,
                                                      const int* __restrict__ etp,
                                                      const int* __restrict__ row_ptr,
                                                      int* __restrict__ cursor,
                                                      unsigned* __restrict__ sorted,
                                                      unsigned short* __restrict__ dst16) {
    int e = blockIdx.x * 256 + threadIdx.x;
    if (e >= N_EDGES) return;
    int d = dstp[e];
    int pos = atomicAdd(cursor + d, 1);
    int j = row_ptr[d] + pos;
    sorted[j] = (unsigned)srcp[e] | ((unsigned)etp[e] << 16);
    dst16[j] = (unsigned short)d;
}

// ---------------- edge-parallel logits --------------------------------------
__global__ __launch_bounds__(256) void logits_kernel(const float* __restrict__ a_q,
                                                     const float* __restrict__ a_k,
                                                     const unsigned* __restrict__ sorted,
                                                     const unsigned short* __restrict__ dst16,
                                                     float* __restrict__ lgt) {
    int j = blockIdx.x * 256 + threadIdx.x;
    if (j >= N_EDGES) return;
    unsigned p = sorted[j];
    int s = p & 0xffff, t = p >> 16;
    int d = dst16[j];
    lgt[j] = lrelu(a_q[t * N_NODES + d] + a_k[t * N_NODES + s]);
}

// ---------------- fused softmax + aggregate + bias + relu ----------------
// xw is column-permuted: position p holds col (p&7)*16 + (p>>3).
// Block = 8 dst nodes: each wave owns 2 nodes in 32-lane halves (deg<=32,
// covers ~all nodes at avg degree 10) -> 2 independent latency chains/wave.
// Full-wave path for deg in (32,64], scalar fallback above. Stores use all
// lanes (xor-reduce leaves sums in every lane).
__device__ inline void accum8(float* acc, uint4 v, float a) {
    const __half2* h2 = reinterpret_cast<const __half2*>(&v);
#pragma unroll
    for (int t = 0; t < 4; ++t) {
        float2 f = __half22float2(h2[t]);
        acc[t * 2]     = fmaf(a, f.x, acc[t * 2]);
        acc[t * 2 + 1] = fmaf(a, f.y, acc[t * 2 + 1]);
    }
}
__device__ inline const uint4* xwrow(const __half* xw, unsigned p, int ln) {
    return (const uint4*)(xw + (((size_t)(p >> 16)) * N_NODES + (p & 0xffff)) * F_DIM + ln * 8);
}

__global__ __launch_bounds__(256) void agg_fused(const __half* __restrict__ xw,
                                                 const float* __restrict__ lgt,
                                                 const int* __restrict__ row_ptr,
                                                 const unsigned* __restrict__ sorted,
                                                 const float* __restrict__ bias,
                                                 float* __restrict__ outp,
                                                 _Float16* __restrict__ hfp) {
    const int lane = threadIdx.x & 63;
    const int wave = threadIdx.x >> 6;
    const int half = lane >> 5, hl = lane & 31;
    const int d0 = blockIdx.x * 8 + wave * 2;
    if (d0 >= N_NODES) return;
    const int dmy = d0 + half;
    const int dv = (dmy < N_NODES) ? dmy : (N_NODES - 1);
    const int beg = row_ptr[dv], end = row_ptr[dv + 1];
    int cnt = (dmy < N_NODES) ? (end - beg) : 0;
    const int cntO = __shfl_xor(cnt, 32);
    const int cmax = (cnt > cntO) ? cnt : cntO;

    if (cmax <= 32) {
        // ---- half-wave path: one node per 32-lane half ----
        unsigned p = 0;
        float l = -3.4e38f;
        if (hl < cnt) {
            p = sorted[beg + hl];
            l = lgt[beg + hl];
        }
        float m = l;
#pragma unroll
        for (int off = 16; off > 0; off >>= 1) m = fmaxf(m, __shfl_xor(m, off, 32));
        const float ex = (hl < cnt) ? __expf(l - m) : 0.f;

        const int gg = hl >> 4, ln = hl & 15;
        float acc[8] = {0, 0, 0, 0, 0, 0, 0, 0};
        // indices i+2+gg <= 31 always (i <= cnt-1 <= 31, step 4), no wrap;
        // lanes >= cnt hold ex=0 so no masking needed.
        for (int i = 0; i < cnt; i += 4) {
            unsigned p0 = __shfl(p, i + gg, 32);
            unsigned p1 = __shfl(p, i + 2 + gg, 32);
            float a0 = __shfl(ex, i + gg, 32);
            float a1 = __shfl(ex, i + 2 + gg, 32);
            uint4 v0 = *xwrow(xw, p0, ln);
            uint4 v1 = *xwrow(xw, p1, ln);
            accum8(acc, v0, a0);
            accum8(acc, v1, a1);
        }
        float dsum = ex;
#pragma unroll
        for (int off = 16; off > 0; off >>= 1) dsum += __shfl_xor(dsum, off, 32);
#pragma unroll
        for (int t = 0; t < 8; ++t) acc[t] += __shfl_xor(acc[t], 16, 32);

        if (dmy < N_NODES) {
            const float inv = 1.f / (dsum + 1e-16f);
#pragma unroll
            for (int j = 0; j < 4; ++j) {
                const int t = gg * 4 + j;
                const int col = t * 16 + ln;
                const float v = fmaxf(fmaf(acc[t], inv, bias[col]), 0.f);
                if (outp) outp[(size_t)dmy * F_DIM + col] = v;
                if (hfp)  hfp[(size_t)dmy * F_DIM + col] = (_Float16)v;
            }
        }
    } else {
        // ---- rare: process each node with the full wave sequentially ----
        const int g = lane >> 4, ln = lane & 15;
        for (int h = 0; h < 2; ++h) {
            const int dd = d0 + h;
            if (dd >= N_NODES) continue;
            const int b = __shfl(beg, h * 32);
            const int c = __shfl(cnt, h * 32);
            if (c <= 64) {
                unsigned p = 0;
                float l = -3.4e38f;
                if (lane < c) {
                    p = sorted[b + lane];
                    l = lgt[b + lane];
                }
                float m = l;
#pragma unroll
                for (int off = 32; off > 0; off >>= 1) m = fmaxf(m, __shfl_xor(m, off));
                const float ex = (lane < c) ? __expf(l - m) : 0.f;
                float acc[8] = {0, 0, 0, 0, 0, 0, 0, 0};
                for (int i = 0; i < c; i += 8) {
                    unsigned p0 = __shfl(p, i + g);
                    unsigned p1 = __shfl(p, i + 4 + g);
                    float a0 = __shfl(ex, i + g);
                    float a1 = __shfl(ex, i + 4 + g);
                    uint4 v0 = *xwrow(xw, p0, ln);
                    uint4 v1 = *xwrow(xw, p1, ln);
                    accum8(acc, v0, a0);
                    accum8(acc, v1, a1);
                }
                float dsum = ex;
#pragma unroll
                for (int off = 32; off > 0; off >>= 1) dsum += __shfl_xor(dsum, off);
#pragma unroll
                for (int t = 0; t < 8; ++t) {
                    acc[t] += __shfl_xor(acc[t], 16);
                    acc[t] += __shfl_xor(acc[t], 32);
                }
                const float inv = 1.f / (dsum + 1e-16f);
#pragma unroll
                for (int j = 0; j < 2; ++j) {
                    const int t = g * 2 + j;
                    const int col = t * 16 + ln;
                    const float v = fmaxf(fmaf(acc[t], inv, bias[col]), 0.f);
                    if (outp) outp[(size_t)dd * F_DIM + col] = v;
                    if (hfp)  hfp[(size_t)dd * F_DIM + col] = (_Float16)v;
                }
            } else {
                // very-high-degree fallback: per-lane 2-col scalar path
                const int p0 = lane * 2;
                const int c0 = (p0 & 7) * 16 + (p0 >> 3);
                const int c1 = c0 + 16;
                float2 acc = make_float2(bias[c0], bias[c1]);
                float m = -3.4e38f;
                for (int i = b + lane; i < b + c; i += 64) m = fmaxf(m, lgt[i]);
#pragma unroll
                for (int off = 32; off > 0; off >>= 1) m = fmaxf(m, __shfl_xor(m, off));
                float dsum = 0.f;
                for (int i = b + lane; i < b + c; i += 64) dsum += __expf(lgt[i] - m);
#pragma unroll
                for (int off = 32; off > 0; off >>= 1) dsum += __shfl_xor(dsum, off);
                const float inv = 1.f / (dsum + 1e-16f);
                for (int i = b; i < b + c; ++i) {
                    unsigned pp = sorted[i];
                    float alpha = __expf(lgt[i] - m) * inv;
                    const __half2 h2 = *((const __half2*)xw + (((size_t)(pp >> 16)) * N_NODES + (pp & 0xffff)) * (F_DIM / 2) + lane);
                    float2 v = make_float2(__half2float(h2.x), __half2float(h2.y));
                    acc.x = fmaf(alpha, v.x, acc.x);
                    acc.y = fmaf(alpha, v.y, acc.y);
                }
                const float v0 = fmaxf(acc.x, 0.f), v1 = fmaxf(acc.y, 0.f);
                if (outp) { outp[(size_t)dd * F_DIM + c0] = v0; outp[(size_t)dd * F_DIM + c1] = v1; }
                if (hfp)  { hfp[(size_t)dd * F_DIM + c0] = (_Float16)v0; hfp[(size_t)dd * F_DIM + c1] = (_Float16)v1; }
            }
        }
    }
}

// ---------------- driver ----------------

extern "C" void kernel_launch(void* const* d_in, const int* in_sizes, int n_in,
                              void* d_out, int out_size, void* d_ws, size_t ws_size,
                              hipStream_t stream) {
    const float* x     = (const float*)d_in[0];
    const float* W     = (const float*)d_in[1];
    const float* att_q = (const float*)d_in[2];
    const float* att_k = (const float*)d_in[3];
    const float* bias  = (const float*)d_in[4];
    const int* ei      = (const int*)d_in[5];
    const int* etp     = (const int*)d_in[6];
    const int* srcp = ei;
    const int* dstp = ei + N_EDGES;
    float* out = (float*)d_out;
    char* ws   = (char*)d_ws;

    size_t off = 0;
    auto alloc = [&](size_t bytes) {
        void* p = ws + off;
        off = (off + bytes + 511) & ~(size_t)511;
        return p;
    };
    __half* xw       = (__half*)alloc((size_t)N_REL * N_NODES * F_DIM * sizeof(__half));
    float* a_q       = (float*)alloc((size_t)N_REL * N_NODES * sizeof(float));
    float* a_k       = (float*)alloc((size_t)N_REL * N_NODES * sizeof(float));
    int* cnt         = (int*)alloc((size_t)2 * N_NODES * sizeof(int));  // cnt + cursor, one memset
    int* cursor      = cnt + N_NODES;
    int* row_ptr     = (int*)alloc(((size_t)N_NODES + 1) * sizeof(int));
    int* partial     = (int*)alloc(256 * sizeof(int));
    unsigned* sorted = (unsigned*)alloc((size_t)N_EDGES * sizeof(unsigned));
    unsigned short* dst16 = (unsigned short*)alloc((size_t)N_EDGES * sizeof(unsigned short));
    float* lgt       = (float*)alloc((size_t)N_EDGES * sizeof(float));
    _Float16* Wf     = (_Float16*)alloc((size_t)N_LAYERS * N_REL * F_DIM * F_DIM * sizeof(_Float16));
    _Float16* Hf     = (_Float16*)alloc((size_t)N_NODES * F_DIM * sizeof(_Float16));

    prep_w<<<N_LAYERS * N_REL, 256, 0, stream>>>(W, Wf);
    hipMemsetAsync(cnt, 0, (size_t)2 * N_NODES * 4, stream);
    count_kernel<<<(N_EDGES + 255) / 256, 256, 0, stream>>>(dstp, cnt);
    block_sum_kernel<<<NBLK_N, 256, 0, stream>>>(cnt, partial);
    scan_partials_kernel<<<1, 256, 0, stream>>>(partial, row_ptr);
    scan_block_kernel<<<NBLK_N, 256, 0, stream>>>(cnt, partial, row_ptr);
    scatter_kernel<<<(N_EDGES + 255) / 256, 256, 0, stream>>>(
        srcp, dstp, etp, row_ptr, cursor, sorted, dst16);

    const int grid_h = (N_NODES * F_DIM / 8 + 255) / 256;   // 3125
    const int grid_m = (N_NODES + GBM - 1) / GBM;           // 98
    const int grid_e = (N_EDGES + 255) / 256;               // 1954
    prep_h<<<grid_h, 256, 0, stream>>>(x, Hf);              // layer-0 input only
    for (int l = 0; l < N_LAYERS; ++l) {
        gemm_xw<<<dim3(grid_m, N_REL), 256, 0, stream>>>(
            Hf, Wf + (size_t)l * N_REL * F_DIM * F_DIM,
            att_q + l * F_DIM, att_k + l * F_DIM,
            xw, a_q, a_k);
        logits_kernel<<<grid_e, 256, 0, stream>>>(a_q, a_k, sorted, dst16, lgt);
        const bool last = (l == N_LAYERS - 1);
        agg_fused<<<(N_NODES + 7) / 8, 256, 0, stream>>>(
            xw, lgt, row_ptr, sorted, bias + l * F_DIM,
            last ? out : nullptr,
            last ? nullptr : Hf);
    }
}